// Round 1
// baseline (559.577 us; speedup 1.0000x reference)
//
#include <hip/hip_runtime.h>

#define N_NODES 100000
#define N_EDGES 1600000
#define IN_F 512
#define HID 64
#define N_CLS 32

__device__ __forceinline__ unsigned short f2bf(float f) {
  unsigned int u = __float_as_uint(f);
  u += 0x7FFFu + ((u >> 16) & 1u);   // round-to-nearest-even
  return (unsigned short)(u >> 16);
}
__device__ __forceinline__ float bf2f(unsigned short s) {
  return __uint_as_float(((unsigned int)s) << 16);
}

// ---------- CSR build ----------
__global__ __launch_bounds__(256) void hist_k(const int* __restrict__ ei, int* __restrict__ cnt) {
  int e = blockIdx.x * 256 + threadIdx.x;
  if (e < N_EDGES) atomicAdd(&cnt[ei[N_EDGES + e]], 1);
}

// block scans 1024 counts (4/thread), writes within-block inclusive to incl[], block total to aux[]
__global__ __launch_bounds__(256) void scan_blocks_k(const int* __restrict__ cnt,
                                                     int* __restrict__ incl,
                                                     int* __restrict__ aux) {
  __shared__ int wsum[4];
  int tid = threadIdx.x;
  int lane = tid & 63, wid = tid >> 6;
  int i0 = blockIdx.x * 1024 + tid * 4;
  int4 v = make_int4(0, 0, 0, 0);
  if (i0 + 3 < N_NODES) v = *(const int4*)(cnt + i0);
  else {
    if (i0 < N_NODES)     v.x = cnt[i0];
    if (i0 + 1 < N_NODES) v.y = cnt[i0 + 1];
    if (i0 + 2 < N_NODES) v.z = cnt[i0 + 2];
  }
  int s1 = v.x, s2 = s1 + v.y, s3 = s2 + v.z, s4 = s3 + v.w;
  int s = s4;
  for (int off = 1; off < 64; off <<= 1) { int t = __shfl_up(s, off); if (lane >= off) s += t; }
  if (lane == 63) wsum[wid] = s;
  __syncthreads();
  int wpre = 0;
  for (int w = 0; w < wid; ++w) wpre += wsum[w];
  int pre = wpre + s - s4;  // exclusive prefix for this thread's 4 elements
  if (i0 < N_NODES)     incl[i0]     = pre + s1;
  if (i0 + 1 < N_NODES) incl[i0 + 1] = pre + s2;
  if (i0 + 2 < N_NODES) incl[i0 + 2] = pre + s3;
  if (i0 + 3 < N_NODES) incl[i0 + 3] = pre + s4;
  if (tid == 255) aux[blockIdx.x] = wpre + s;  // block total
}

__global__ __launch_bounds__(128) void scan_aux_k(int* aux, int nb) {
  __shared__ int w0s;
  int tid = threadIdx.x, lane = tid & 63, wid = tid >> 6;
  int v = (tid < nb) ? aux[tid] : 0;
  int s = v;
  for (int off = 1; off < 64; off <<= 1) { int t = __shfl_up(s, off); if (lane >= off) s += t; }
  if (tid == 63) w0s = s;
  __syncthreads();
  int incl = s + (wid ? w0s : 0);
  if (tid < nb) aux[tid] = incl - v;  // exclusive block offsets
}

__global__ __launch_bounds__(256) void finalize_k(const int* __restrict__ cnt,
                                                  int* __restrict__ rowptr,
                                                  const int* __restrict__ aux,
                                                  int* __restrict__ cursor,
                                                  float* __restrict__ dinv) {
  int i = blockIdx.x * 256 + threadIdx.x;
  if (i == 0) rowptr[0] = 0;
  if (i < N_NODES) {
    int r = rowptr[i + 1] + aux[i >> 10];
    rowptr[i + 1] = r;
    int c = cnt[i];
    cursor[i] = r - c;                     // exclusive start
    dinv[i] = rsqrtf((float)(c + 1));      // +1 self-loop
  }
}

__global__ __launch_bounds__(256) void fill_k(const int* __restrict__ ei,
                                              int* __restrict__ cursor,
                                              int* __restrict__ srcs) {
  int e = blockIdx.x * 256 + threadIdx.x;
  if (e < N_EDGES) {
    int s = ei[e], d = ei[N_EDGES + e];
    int p = atomicAdd(&cursor[d], 1);
    srcs[p] = s;
  }
}

// ---------- GEMM1: h0 = x @ W1  (100000x512 @ 512x64), bf16 out ----------
__global__ __launch_bounds__(256) void gemm1_k(const float* __restrict__ x,
                                               const float* __restrict__ W1,
                                               unsigned short* __restrict__ h0) {
  __shared__ float xs[64][33];   // +1 pad breaks bank conflicts on column reads
  __shared__ float wl[32][64];
  int tid = threadIdx.x;
  int tx = tid & 15, ty = tid >> 4;
  int row0 = blockIdx.x * 64;
  float acc[4][4] = {{0.f}};
  for (int k0 = 0; k0 < IN_F; k0 += 32) {
    for (int f = tid; f < 512; f += 256) {         // 64x32 x-tile as float4
      int r = f >> 3, c4 = (f & 7) << 2;
      float4 v = make_float4(0.f, 0.f, 0.f, 0.f);
      int gr = row0 + r;
      if (gr < N_NODES) v = *(const float4*)(x + (size_t)gr * IN_F + k0 + c4);
      xs[r][c4] = v.x; xs[r][c4 + 1] = v.y; xs[r][c4 + 2] = v.z; xs[r][c4 + 3] = v.w;
    }
    for (int f = tid; f < 512; f += 256) {         // 32x64 W1-tile
      int r = f >> 4, c4 = (f & 15) << 2;
      *(float4*)&wl[r][c4] = *(const float4*)(W1 + (size_t)(k0 + r) * HID + c4);
    }
    __syncthreads();
    #pragma unroll 8
    for (int k = 0; k < 32; ++k) {
      float a0 = xs[ty * 4 + 0][k], a1 = xs[ty * 4 + 1][k];
      float a2 = xs[ty * 4 + 2][k], a3 = xs[ty * 4 + 3][k];
      float4 b = *(const float4*)&wl[k][tx * 4];
      acc[0][0] += a0 * b.x; acc[0][1] += a0 * b.y; acc[0][2] += a0 * b.z; acc[0][3] += a0 * b.w;
      acc[1][0] += a1 * b.x; acc[1][1] += a1 * b.y; acc[1][2] += a1 * b.z; acc[1][3] += a1 * b.w;
      acc[2][0] += a2 * b.x; acc[2][1] += a2 * b.y; acc[2][2] += a2 * b.z; acc[2][3] += a2 * b.w;
      acc[3][0] += a3 * b.x; acc[3][1] += a3 * b.y; acc[3][2] += a3 * b.z; acc[3][3] += a3 * b.w;
    }
    __syncthreads();
  }
  for (int i = 0; i < 4; ++i) {
    int gr = row0 + ty * 4 + i;
    if (gr < N_NODES) {
      ushort4 st;
      st.x = f2bf(acc[i][0]); st.y = f2bf(acc[i][1]);
      st.z = f2bf(acc[i][2]); st.w = f2bf(acc[i][3]);
      *(ushort4*)(h0 + (size_t)gr * HID + tx * 4) = st;
    }
  }
}

// ---------- agg1: h = relu(dinv[d]*(sum dinv[s]*h0[s] + dinv[d]*h0[d]) + b1) ----------
__global__ __launch_bounds__(256) void agg1_k(const unsigned short* __restrict__ h0,
                                              const int* __restrict__ rowptr,
                                              const int* __restrict__ srcs,
                                              const float* __restrict__ dinv,
                                              const float* __restrict__ b1,
                                              float* __restrict__ out) {
  int idx = blockIdx.x * 256 + threadIdx.x;
  int node = idx >> 6, lane = idx & 63;
  if (node >= N_NODES) return;
  float dn = dinv[node];
  float acc = dn * bf2f(h0[(size_t)node * HID + lane]);  // self-loop
  int p1 = rowptr[node + 1];
  for (int p = rowptr[node]; p < p1; ++p) {
    int s = srcs[p];
    acc += dinv[s] * bf2f(h0[(size_t)s * HID + lane]);
  }
  float v = dn * acc + b1[lane];
  out[(size_t)node * HID + lane] = fmaxf(v, 0.f);
}

// ---------- GEMM2: h2 = h @ W2 (100000x64 @ 64x32) ----------
__global__ __launch_bounds__(256) void gemm2_k(const float* __restrict__ h,
                                               const float* __restrict__ W2,
                                               float* __restrict__ h2) {
  __shared__ float w2s[HID * N_CLS];
  __shared__ float hs[8][HID];
  int tid = threadIdx.x;
  for (int i = tid; i < HID * N_CLS; i += 256) w2s[i] = W2[i];
  int node0 = blockIdx.x * 8;
  for (int i = tid; i < 8 * HID; i += 256) {
    int r = i >> 6, c = i & 63;
    int g = node0 + r;
    hs[r][c] = (g < N_NODES) ? h[(size_t)g * HID + c] : 0.f;
  }
  __syncthreads();
  int nl = tid >> 5, cls = tid & 31;
  float acc = 0.f;
  #pragma unroll
  for (int k = 0; k < HID; ++k) acc += hs[nl][k] * w2s[k * N_CLS + cls];
  int g = node0 + nl;
  if (g < N_NODES) h2[(size_t)g * N_CLS + cls] = acc;
}

// ---------- agg2: z = dinv[d]*(sum dinv[s]*h2[s] + dinv[d]*h2[d]) + b2 ----------
__global__ __launch_bounds__(256) void agg2_k(const float* __restrict__ h2,
                                              const int* __restrict__ rowptr,
                                              const int* __restrict__ srcs,
                                              const float* __restrict__ dinv,
                                              const float* __restrict__ b2,
                                              float* __restrict__ out) {
  int idx = blockIdx.x * 256 + threadIdx.x;
  int node = idx >> 5, f = idx & 31;
  if (node >= N_NODES) return;
  float dn = dinv[node];
  float acc = dn * h2[(size_t)node * N_CLS + f];  // self-loop
  int p1 = rowptr[node + 1];
  for (int p = rowptr[node]; p < p1; ++p) {
    int s = srcs[p];
    acc += dinv[s] * h2[(size_t)s * N_CLS + f];
  }
  out[(size_t)node * N_CLS + f] = dn * acc + b2[f];
}

extern "C" void kernel_launch(void* const* d_in, const int* in_sizes, int n_in,
                              void* d_out, int out_size, void* d_ws, size_t ws_size,
                              hipStream_t stream) {
  const float* x  = (const float*)d_in[0];
  const int*   ei = (const int*)d_in[1];
  const float* W1 = (const float*)d_in[2];
  const float* b1 = (const float*)d_in[3];
  const float* W2 = (const float*)d_in[4];
  const float* b2 = (const float*)d_in[5];
  float* out_h = (float*)d_out;
  float* out_z = out_h + (size_t)N_NODES * HID;

  char* ws = (char*)d_ws;
  int* cnt            = (int*)(ws + 0);                 // 400 KB
  int* rowptr         = (int*)(ws + (512 << 10));       // 400 KB (+4)
  int* cursor         = (int*)(ws + (1024 << 10));      // 400 KB
  int* aux            = (int*)(ws + (1536 << 10));      // <1 KB
  float* dinv         = (float*)(ws + (1600 << 10));    // 400 KB
  int* srcs           = (int*)(ws + (2ull << 20));      // 6.4 MB
  unsigned short* h0  = (unsigned short*)(ws + (9ull << 20));   // 12.8 MB
  float* h2           = (float*)(ws + (22ull << 20));   // 12.8 MB

  int nb = (N_NODES + 1023) / 1024;

  hipMemsetAsync(cnt, 0, N_NODES * sizeof(int), stream);
  hist_k<<<(N_EDGES + 255) / 256, 256, 0, stream>>>(ei, cnt);
  scan_blocks_k<<<nb, 256, 0, stream>>>(cnt, rowptr + 1, aux);
  scan_aux_k<<<1, 128, 0, stream>>>(aux, nb);
  finalize_k<<<(N_NODES + 255) / 256, 256, 0, stream>>>(cnt, rowptr, aux, cursor, dinv);
  fill_k<<<(N_EDGES + 255) / 256, 256, 0, stream>>>(ei, cursor, srcs);
  gemm1_k<<<(N_NODES + 63) / 64, 256, 0, stream>>>(x, W1, h0);
  agg1_k<<<(N_NODES * 64) / 256, 256, 0, stream>>>(h0, rowptr, srcs, dinv, b1, out_h);
  gemm2_k<<<(N_NODES + 7) / 8, 256, 0, stream>>>(out_h, W2, h2);
  agg2_k<<<(N_NODES * 32) / 256, 256, 0, stream>>>(h2, rowptr, srcs, dinv, b2, out_z);
}

// Round 2
// 381.631 us; speedup vs baseline: 1.4663x; 1.4663x over previous
//
#include <hip/hip_runtime.h>

#define N_NODES 100000
#define N_EDGES 1600000
#define IN_F 512
#define HID 64
#define N_CLS 32

typedef __attribute__((ext_vector_type(8))) short short8;
typedef __attribute__((ext_vector_type(4))) float f32x4;

__device__ __forceinline__ unsigned short f2bf(float f) {
  unsigned int u = __float_as_uint(f);
  u += 0x7FFFu + ((u >> 16) & 1u);   // round-to-nearest-even
  return (unsigned short)(u >> 16);
}
__device__ __forceinline__ float bf2f(unsigned short s) {
  return __uint_as_float(((unsigned int)s) << 16);
}

// ---------- CSR build ----------
__global__ __launch_bounds__(256) void hist_k(const int* __restrict__ ei, int* __restrict__ cnt) {
  int e = blockIdx.x * 256 + threadIdx.x;
  if (e < N_EDGES) atomicAdd(&cnt[ei[N_EDGES + e]], 1);
}

__global__ __launch_bounds__(256) void scan_blocks_k(const int* __restrict__ cnt,
                                                     int* __restrict__ incl,
                                                     int* __restrict__ aux) {
  __shared__ int wsum[4];
  int tid = threadIdx.x;
  int lane = tid & 63, wid = tid >> 6;
  int i0 = blockIdx.x * 1024 + tid * 4;
  int4 v = make_int4(0, 0, 0, 0);
  if (i0 + 3 < N_NODES) v = *(const int4*)(cnt + i0);
  else {
    if (i0 < N_NODES)     v.x = cnt[i0];
    if (i0 + 1 < N_NODES) v.y = cnt[i0 + 1];
    if (i0 + 2 < N_NODES) v.z = cnt[i0 + 2];
  }
  int s1 = v.x, s2 = s1 + v.y, s3 = s2 + v.z, s4 = s3 + v.w;
  int s = s4;
  for (int off = 1; off < 64; off <<= 1) { int t = __shfl_up(s, off); if (lane >= off) s += t; }
  if (lane == 63) wsum[wid] = s;
  __syncthreads();
  int wpre = 0;
  for (int w = 0; w < wid; ++w) wpre += wsum[w];
  int pre = wpre + s - s4;
  if (i0 < N_NODES)     incl[i0]     = pre + s1;
  if (i0 + 1 < N_NODES) incl[i0 + 1] = pre + s2;
  if (i0 + 2 < N_NODES) incl[i0 + 2] = pre + s3;
  if (i0 + 3 < N_NODES) incl[i0 + 3] = pre + s4;
  if (tid == 255) aux[blockIdx.x] = wpre + s;
}

__global__ __launch_bounds__(128) void scan_aux_k(int* aux, int nb) {
  __shared__ int w0s;
  int tid = threadIdx.x, lane = tid & 63, wid = tid >> 6;
  int v = (tid < nb) ? aux[tid] : 0;
  int s = v;
  for (int off = 1; off < 64; off <<= 1) { int t = __shfl_up(s, off); if (lane >= off) s += t; }
  if (tid == 63) w0s = s;
  __syncthreads();
  int incl = s + (wid ? w0s : 0);
  if (tid < nb) aux[tid] = incl - v;
}

__global__ __launch_bounds__(256) void finalize_k(const int* __restrict__ cnt,
                                                  int* __restrict__ rowptr,
                                                  const int* __restrict__ aux,
                                                  int* __restrict__ cursor,
                                                  float* __restrict__ dinv) {
  int i = blockIdx.x * 256 + threadIdx.x;
  if (i == 0) rowptr[0] = 0;
  if (i < N_NODES) {
    int r = rowptr[i + 1] + aux[i >> 10];
    rowptr[i + 1] = r;
    int c = cnt[i];
    cursor[i] = r - c;
    dinv[i] = rsqrtf((float)(c + 1));
  }
}

__global__ __launch_bounds__(256) void fill_k(const int* __restrict__ ei,
                                              int* __restrict__ cursor,
                                              int* __restrict__ srcs) {
  int e = blockIdx.x * 256 + threadIdx.x;
  if (e < N_EDGES) {
    int s = ei[e], d = ei[N_EDGES + e];
    int p = atomicAdd(&cursor[d], 1);
    srcs[p] = s;
  }
}

// ---------- W1 transpose to bf16: W1t[n][k] = bf16(W1[k][n]) ----------
__global__ __launch_bounds__(256) void w1t_k(const float* __restrict__ W1,
                                             unsigned short* __restrict__ W1t) {
  int i = blockIdx.x * 256 + threadIdx.x;
  if (i < IN_F * HID) {
    int n = i >> 9, k = i & 511;
    W1t[i] = f2bf(W1[(size_t)k * HID + n]);
  }
}

// ---------- GEMM1 (MFMA bf16): h0s[r][c] = dinv[r] * (x @ W1)[r][c], bf16 ----------
__global__ __launch_bounds__(256) void gemm1_mfma_k(const float* __restrict__ x,
                                                    const unsigned short* __restrict__ W1t,
                                                    const float* __restrict__ dinv,
                                                    unsigned short* __restrict__ h0s) {
  __shared__ __align__(16) char As[64 * 128];   // 64 rows x 64 k, bf16, XOR-swizzled
  __shared__ __align__(16) char Ws[64 * 128];   // 64 n   x 64 k, bf16, XOR-swizzled
  int tid = threadIdx.x;
  int wave = tid >> 6, lane = tid & 63;
  int row0 = blockIdx.x * 64;
  f32x4 acc[4] = {{0.f,0.f,0.f,0.f},{0.f,0.f,0.f,0.f},{0.f,0.f,0.f,0.f},{0.f,0.f,0.f,0.f}};

  int l15 = lane & 15, lhi = lane >> 4;
  int rA = (wave << 4) + l15;                    // local A row for this lane

  for (int k0 = 0; k0 < IN_F; k0 += 64) {
    // stage x tile (64x64 f32 -> bf16)
    #pragma unroll
    for (int i = 0; i < 4; ++i) {
      int f = tid + i * 256;                     // 1024 float4 groups
      int r = f >> 4, c4 = (f & 15) << 2;
      float4 v = make_float4(0.f, 0.f, 0.f, 0.f);
      int gr = row0 + r;
      if (gr < N_NODES) v = *(const float4*)(x + (size_t)gr * IN_F + k0 + c4);
      ushort4 u;
      u.x = f2bf(v.x); u.y = f2bf(v.y); u.z = f2bf(v.z); u.w = f2bf(v.w);
      int byte = r * 128 + (c4 << 1);
      byte ^= (r & 7) << 4;
      *(ushort4*)(As + byte) = u;
    }
    // stage W tile (64n x 64k bf16, already transposed)
    #pragma unroll
    for (int i = 0; i < 2; ++i) {
      int f = tid + i * 256;                     // 512 16B chunks
      int n = f >> 3, k8 = (f & 7) << 3;
      uint4 v = *(const uint4*)(W1t + (size_t)n * IN_F + k0 + k8);
      int byte = n * 128 + (k8 << 1);
      byte ^= (n & 7) << 4;
      *(uint4*)(Ws + byte) = v;
    }
    __syncthreads();
    #pragma unroll
    for (int ks = 0; ks < 64; ks += 32) {
      int kk = ks + (lhi << 3);
      int ba = rA * 128 + (kk << 1); ba ^= (rA & 7) << 4;
      short8 a = *(const short8*)(As + ba);
      #pragma unroll
      for (int j = 0; j < 4; ++j) {
        int nB = (j << 4) + l15;
        int bb = nB * 128 + (kk << 1); bb ^= (nB & 7) << 4;
        short8 b = *(const short8*)(Ws + bb);
        acc[j] = __builtin_amdgcn_mfma_f32_16x16x32_bf16(a, b, acc[j], 0, 0, 0);
      }
    }
    __syncthreads();
  }
  // C: col = lane&15 (+16*j), row = (lane>>4)*4 + r
  int rbase = row0 + (wave << 4) + (lhi << 2);
  #pragma unroll
  for (int r = 0; r < 4; ++r) {
    int gr = rbase + r;
    if (gr < N_NODES) {
      float dn = dinv[gr];
      #pragma unroll
      for (int j = 0; j < 4; ++j)
        h0s[(size_t)gr * HID + (j << 4) + l15] = f2bf(dn * acc[j][r]);
    }
  }
}

// ---------- agg1: h = relu(dinv[d]*(h0s[d] + sum h0s[s]) + b1) ----------
__global__ __launch_bounds__(256) void agg1_k(const unsigned short* __restrict__ h0s,
                                              const int* __restrict__ rowptr,
                                              const int* __restrict__ srcs,
                                              const float* __restrict__ dinv,
                                              const float* __restrict__ b1,
                                              float* __restrict__ out) {
  int idx = blockIdx.x * 256 + threadIdx.x;
  int node = idx >> 6, lane = idx & 63;
  if (node >= N_NODES) return;
  float acc = bf2f(h0s[(size_t)node * HID + lane]);   // self (already dinv-scaled)
  int p = rowptr[node], p1 = rowptr[node + 1];
  for (; p + 4 <= p1; p += 4) {
    int s0 = srcs[p], s1 = srcs[p + 1], s2 = srcs[p + 2], s3 = srcs[p + 3];
    float v0 = bf2f(h0s[(size_t)s0 * HID + lane]);
    float v1 = bf2f(h0s[(size_t)s1 * HID + lane]);
    float v2 = bf2f(h0s[(size_t)s2 * HID + lane]);
    float v3 = bf2f(h0s[(size_t)s3 * HID + lane]);
    acc += (v0 + v1) + (v2 + v3);
  }
  for (; p < p1; ++p) acc += bf2f(h0s[(size_t)srcs[p] * HID + lane]);
  float v = dinv[node] * acc + b1[lane];
  out[(size_t)node * HID + lane] = fmaxf(v, 0.f);
}

// ---------- GEMM2: h2s = dinv * (h @ W2) ----------
__global__ __launch_bounds__(256) void gemm2_k(const float* __restrict__ h,
                                               const float* __restrict__ W2,
                                               const float* __restrict__ dinv,
                                               float* __restrict__ h2s) {
  __shared__ float w2s[HID * N_CLS];
  __shared__ float hs[8][HID];
  int tid = threadIdx.x;
  for (int i = tid; i < HID * N_CLS; i += 256) w2s[i] = W2[i];
  int node0 = blockIdx.x * 8;
  for (int i = tid; i < 8 * HID; i += 256) {
    int r = i >> 6, c = i & 63;
    int g = node0 + r;
    hs[r][c] = (g < N_NODES) ? h[(size_t)g * HID + c] : 0.f;
  }
  __syncthreads();
  int nl = tid >> 5, cls = tid & 31;
  float acc = 0.f;
  #pragma unroll
  for (int k = 0; k < HID; ++k) acc += hs[nl][k] * w2s[k * N_CLS + cls];
  int g = node0 + nl;
  if (g < N_NODES) h2s[(size_t)g * N_CLS + cls] = dinv[g] * acc;
}

// ---------- agg2: z = dinv[d]*(h2s[d] + sum h2s[s]) + b2 ----------
// one wave per node; lanes 0-31 / 32-63 split the edge list
__global__ __launch_bounds__(256) void agg2_k(const float* __restrict__ h2s,
                                              const int* __restrict__ rowptr,
                                              const int* __restrict__ srcs,
                                              const float* __restrict__ dinv,
                                              const float* __restrict__ b2,
                                              float* __restrict__ out) {
  int idx = blockIdx.x * 256 + threadIdx.x;
  int node = idx >> 6;
  if (node >= N_NODES) return;
  int lane = threadIdx.x & 63;
  int f = lane & 31, half = lane >> 5;
  int p0 = rowptr[node], p1 = rowptr[node + 1];
  int hc = (p1 - p0 + 1) >> 1;
  int ps = p0 + (half ? hc : 0);
  int pe = half ? p1 : p0 + hc;
  float acc = half ? 0.f : h2s[(size_t)node * N_CLS + f];  // self
  int p = ps;
  for (; p + 4 <= pe; p += 4) {
    int s0 = srcs[p], s1 = srcs[p + 1], s2 = srcs[p + 2], s3 = srcs[p + 3];
    float v0 = h2s[(size_t)s0 * N_CLS + f];
    float v1 = h2s[(size_t)s1 * N_CLS + f];
    float v2 = h2s[(size_t)s2 * N_CLS + f];
    float v3 = h2s[(size_t)s3 * N_CLS + f];
    acc += (v0 + v1) + (v2 + v3);
  }
  for (; p < pe; ++p) acc += h2s[(size_t)srcs[p] * N_CLS + f];
  acc += __shfl_xor(acc, 32);
  if (!half) out[(size_t)node * N_CLS + f] = dinv[node] * acc + b2[f];
}

extern "C" void kernel_launch(void* const* d_in, const int* in_sizes, int n_in,
                              void* d_out, int out_size, void* d_ws, size_t ws_size,
                              hipStream_t stream) {
  const float* x  = (const float*)d_in[0];
  const int*   ei = (const int*)d_in[1];
  const float* W1 = (const float*)d_in[2];
  const float* b1 = (const float*)d_in[3];
  const float* W2 = (const float*)d_in[4];
  const float* b2 = (const float*)d_in[5];
  float* out_h = (float*)d_out;
  float* out_z = out_h + (size_t)N_NODES * HID;

  char* ws = (char*)d_ws;
  int* cnt            = (int*)(ws + 0);                    // 400 KB
  int* rowptr         = (int*)(ws + (512 << 10));          // 400 KB (+4)
  int* cursor         = (int*)(ws + (1024 << 10));         // 400 KB
  float* dinv         = (float*)(ws + (1536 << 10));       // 400 KB
  int* aux            = (int*)(ws + (1948 << 10));         // <1 KB
  unsigned short* W1t = (unsigned short*)(ws + (1952 << 10)); // 64 KB
  int* srcs           = (int*)(ws + (2048ull << 10));      // 6.4 MB
  unsigned short* h0s = (unsigned short*)(ws + (9ull << 20));  // 12.8 MB
  float* h2s          = (float*)(ws + (22ull << 20));      // 12.8 MB

  int nb = (N_NODES + 1023) / 1024;

  hipMemsetAsync(cnt, 0, N_NODES * sizeof(int), stream);
  w1t_k<<<(IN_F * HID + 255) / 256, 256, 0, stream>>>(W1, W1t);
  hist_k<<<(N_EDGES + 255) / 256, 256, 0, stream>>>(ei, cnt);
  scan_blocks_k<<<nb, 256, 0, stream>>>(cnt, rowptr + 1, aux);
  scan_aux_k<<<1, 128, 0, stream>>>(aux, nb);
  finalize_k<<<(N_NODES + 255) / 256, 256, 0, stream>>>(cnt, rowptr, aux, cursor, dinv);
  fill_k<<<(N_EDGES + 255) / 256, 256, 0, stream>>>(ei, cursor, srcs);
  gemm1_mfma_k<<<(N_NODES + 63) / 64, 256, 0, stream>>>(x, W1t, dinv, h0s);
  agg1_k<<<(N_NODES * 64) / 256, 256, 0, stream>>>(h0s, rowptr, srcs, dinv, b1, out_h);
  gemm2_k<<<(N_NODES + 7) / 8, 256, 0, stream>>>(out_h, W2, dinv, h2s);
  agg2_k<<<(N_NODES * 64 + 255) / 256, 256, 0, stream>>>(h2s, rowptr, srcs, dinv, b2, out_z);
}